// Round 4
// baseline (167.963 us; speedup 1.0000x reference)
//
#include <hip/hip_runtime.h>
#include <math.h>

typedef unsigned int uint;
typedef unsigned short ushort;
typedef __attribute__((ext_vector_type(8))) short bf16x8;
typedef __attribute__((ext_vector_type(4))) float f32x4;

static constexpr int Mdim = 4096;
static constexpr int Ndim = 4096;
static constexpr int Kdim = 4096;
static constexpr int Hdim = 4096;

// ---------------- numerics helpers ----------------

__device__ __forceinline__ float fp8_round(float v) {
  float a = fabsf(v);
  float q;
  if (a >= 0x1p-6f) {           // normal range: quantum 2^(e-3)
    uint u = __float_as_uint(a);
    int e = (int)(u >> 23) - 127;
    float quant = __uint_as_float((uint)(e - 3 + 127) << 23);
    q = rintf(a / quant) * quant;
    q = fminf(q, 448.f);
  } else {                      // subnormal: quantum 2^-9
    q = rintf(a * 512.f) * 0x1p-9f;
  }
  return copysignf(q, v);
}

__device__ __forceinline__ float e2m1_round(float t) {
  float a = fabsf(t);
  float q;
  if (a <= 0.25f) q = 0.f;
  else if (a <= 0.75f) q = 0.5f;
  else if (a <= 1.25f) q = 1.f;
  else if (a <= 1.75f) q = 1.5f;
  else if (a <= 2.5f)  q = 2.f;
  else if (a <= 3.5f)  q = 3.f;
  else if (a <= 5.f)   q = 4.f;
  else                 q = 6.f;
  return copysignf(q, t);
}

__device__ __forceinline__ float e2m1_decode(uint c) {
  uint m = c & 7u;
  float v;
  if (m == 0u) v = 0.f;
  else if (m == 1u) v = 0.5f;
  else v = __uint_as_float(((126u + (m >> 1)) << 23) | ((m & 1u) << 22));
  return (c & 8u) ? -v : v;
}

// ---------------- kernel 1: SiLU-mul + NVFP4 fake-quant -> bf16 a_deq ----------------

__global__ void silu_quant_kernel(const float* __restrict__ x, ushort* __restrict__ a_deq,
                                  const float* __restrict__ scalep) {
  const int g = blockIdx.x * 256 + threadIdx.x;
  const int row = g >> 8;
  const int blk = g & 255;
  const float gs = 1.0f / scalep[0];
  const float c6 = gs / 6.0f;
  const float* gp = x + (size_t)row * (2 * Hdim) + blk * 16;
  const float* up = gp + Hdim;
  float y[16];
  float amax = 0.f;
#pragma unroll
  for (int i = 0; i < 4; ++i) {
    float4 gv = ((const float4*)gp)[i];
    float4 uv = ((const float4*)up)[i];
    float ga[4] = {gv.x, gv.y, gv.z, gv.w};
    float ua[4] = {uv.x, uv.y, uv.z, uv.w};
#pragma unroll
    for (int j = 0; j < 4; ++j) {
      float xv = ga[j];
      float sig = 1.0f / (1.0f + expf(-xv));
      float yy = xv * sig * ua[j];
      y[i * 4 + j] = yy;
      amax = fmaxf(amax, fabsf(yy));
    }
  }
  const float sf = fp8_round(amax * c6);
  uint outp[8];
  if (sf > 0.f) {
    const float inv = gs / sf;
#pragma unroll
    for (int i = 0; i < 8; ++i) {
      float t0 = fminf(fmaxf(y[2 * i] * inv, -6.f), 6.f);
      float t1 = fminf(fmaxf(y[2 * i + 1] * inv, -6.f), 6.f);
      float d0 = e2m1_round(t0) * sf;
      float d1 = e2m1_round(t1) * sf;
      outp[i] = (__float_as_uint(d0) >> 16) | ((__float_as_uint(d1) >> 16) << 16);
    }
  } else {
#pragma unroll
    for (int i = 0; i < 8; ++i) outp[i] = 0u;
  }
  uint4* dst = (uint4*)(a_deq + (size_t)row * Hdim + blk * 16);
  dst[0] = (uint4){outp[0], outp[1], outp[2], outp[3]};
  dst[1] = (uint4){outp[4], outp[5], outp[6], outp[7]};
}

// ---------------- kernel 2: weight dequant -> bf16 b_deq ----------------

__global__ void wdeq_kernel(const int* __restrict__ w, const float* __restrict__ wscale,
                            ushort* __restrict__ b_deq) {
  const int g = blockIdx.x * 256 + threadIdx.x;
  const int n = g >> 8;
  const int blk = g & 255;
  const int4* wp = (const int4*)(w + (size_t)n * (Hdim / 2) + blk * 8);
  int4 w0 = wp[0], w1 = wp[1];
  int wb[8] = {w0.x, w0.y, w0.z, w0.w, w1.x, w1.y, w1.z, w1.w};
  const float ws = fp8_round(wscale[(size_t)n * (Hdim / 16) + blk]);
  uint outp[8];
#pragma unroll
  for (int i = 0; i < 8; ++i) {
    uint byte = (uint)wb[i] & 0xFFu;
    float vlo = e2m1_decode(byte & 15u) * ws;
    float vhi = e2m1_decode(byte >> 4) * ws;
    outp[i] = (__float_as_uint(vlo) >> 16) | ((__float_as_uint(vhi) >> 16) << 16);
  }
  uint4* dst = (uint4*)(b_deq + (size_t)n * Hdim + blk * 16);
  dst[0] = (uint4){outp[0], outp[1], outp[2], outp[3]};
  dst[1] = (uint4){outp[4], outp[5], outp[6], outp[7]};
}

// ---------------- kernel 3: 256x256 bf16 GEMM, pinned m201-style 4-phase schedule ----------------
// 8 waves (2M x 4N), BK=64, 2-slot LDS (128 KiB). Per phase: read THIS phase's
// fragments -> stage 1 half-tile -> barrier -> per-wave lgkmcnt(0) (staggers waves,
// DS pipe serves later waves during earlier waves' MFMA) -> sched_barrier pin ->
// setprio MFMA cluster -> barrier. Counted vmcnt(4) only at q3.
// Stage ledger (during tile u): q0 A(u+1)h0, q1 A(u+1)h1 (other slot A; prev
// occupant's reads ended q3(u-1)); q2 B(u+2)h0, q3 B(u+2)h1 (CURRENT slot B;
// B(u) reads complete at q0 close, 2 barriers before issue). vmcnt(4)@q3 forces
// A(u+1)+B(u+1) landed, keeps B(u+2) (4 loads) in flight.

#define BM 256
#define BN 256
#define BK 64
#define NT (Kdim / BK)
#define TILE_E (256 * 64)     // 16384 ushort = 32 KB

__device__ __forceinline__ void gload_lds16(const ushort* g, ushort* l) {
  __builtin_amdgcn_global_load_lds((const __attribute__((address_space(1))) void*)g,
                                   (__attribute__((address_space(3))) void*)l,
                                   16, 0, 0);
}

#define STAGE(dst, mat, goff, h, kcol)                                        \
  do {                                                                        \
    gload_lds16((mat) + (size_t)goff[(h)*2 + 0] + (kcol), (dst) + loff[(h)*2 + 0]); \
    gload_lds16((mat) + (size_t)goff[(h)*2 + 1] + (kcol), (dst) + loff[(h)*2 + 1]); \
  } while (0)

__global__ __launch_bounds__(512, 2) void gemm256(const ushort* __restrict__ A,
                                                  const ushort* __restrict__ B,
                                                  float* __restrict__ C,
                                                  const float* __restrict__ scalep,
                                                  const float* __restrict__ wscale2p) {
  extern __shared__ __align__(16) ushort lds[];   // 131072 B
  const int tid = threadIdx.x;
  const int wave = tid >> 6;
  const int lane = tid & 63;
  const int wm = wave >> 2;
  const int wn = wave & 3;
  const int fr = lane & 15;
  const int fq = lane >> 4;

  const int wg = blockIdx.x;
  const int swz = (wg & 7) * 32 + (wg >> 3);      // 256 % 8 == 0 -> bijective
  const int m0 = (swz >> 4) * BM;
  const int n0 = (swz & 15) * BN;

  f32x4 acc[8][4];
#pragma unroll
  for (int i = 0; i < 8; ++i)
#pragma unroll
    for (int j = 0; j < 4; ++j) acc[i][j] = (f32x4){0.f, 0.f, 0.f, 0.f};

  ushort* A0 = lds;                 // A slot0
  ushort* A1 = lds + TILE_E;        // A slot1
  ushort* B0 = lds + 2 * TILE_E;    // B slot0
  ushort* B1 = lds + 3 * TILE_E;    // B slot1

  // staging geometry: row = h*128 + rr*64 + wave*8 + lane/8 ; source chunk
  // pre-swizzled (c ^ (row&7)) so LDS holds the XOR-swizzled layout.
  int goffA[4], goffB[4], loff[4];
#pragma unroll
  for (int h = 0; h < 2; ++h)
#pragma unroll
    for (int rr = 0; rr < 2; ++rr) {
      const int idx = h * 2 + rr;
      const int rowb = h * 128 + rr * 64 + wave * 8;
      const int trow = rowb + (lane >> 3);
      const int sc = (lane & 7) ^ (trow & 7);
      goffA[idx] = (m0 + trow) * Kdim + sc * 8;
      goffB[idx] = (n0 + trow) * Kdim + sc * 8;
      loff[idx] = rowb * 64;
    }

  // fragment read geometry: offset(r,ck) = r*64 + ((ck ^ (r&7))*8); r&7 == fr&7
  const int laneAOff = (wm * 128 + fr) * 64;
  const int laneBOff = (wn * 64 + fr) * 64;
  const int xo0 = (fq ^ (fr & 7)) * 8;
  const int xo1 = ((4 + fq) ^ (fr & 7)) * 8;

  // ---- prologue: A(0), B(0), B(1); force A0+B0 landed, B(1) in flight ----
  STAGE(A0, A, goffA, 0, 0);  STAGE(A0, A, goffA, 1, 0);
  STAGE(B0, B, goffB, 0, 0);  STAGE(B0, B, goffB, 1, 0);
  STAGE(B1, B, goffB, 0, BK); STAGE(B1, B, goffB, 1, BK);
  asm volatile("s_waitcnt vmcnt(4)" ::: "memory");
  __builtin_amdgcn_s_barrier();
  __builtin_amdgcn_sched_barrier(0);

#define MFMA_CLUSTER(base)                                                       \
  do {                                                                           \
    __builtin_amdgcn_s_setprio(1);                                               \
    _Pragma("unroll")                                                            \
    for (int m2 = 0; m2 < 2; ++m2)                                               \
      _Pragma("unroll")                                                          \
      for (int ni = 0; ni < 4; ++ni)                                             \
        _Pragma("unroll")                                                        \
        for (int kk = 0; kk < 2; ++kk)                                           \
          acc[(base) + m2][ni] = __builtin_amdgcn_mfma_f32_16x16x32_bf16(        \
              af[m2][kk], bfr[ni][kk], acc[(base) + m2][ni], 0, 0, 0);           \
    __builtin_amdgcn_s_setprio(0);                                               \
    __builtin_amdgcn_sched_barrier(0);                                           \
  } while (0)

  for (int u = 0; u < NT; ++u) {
    ushort* sA = (u & 1) ? A1 : A0;
    ushort* sB = (u & 1) ? B1 : B0;
    ushort* dA = (u & 1) ? A0 : A1;     // A(u+1) target
    ushort* dB = sB;                     // B(u+2) target (current B slot)
    const int kA = (u + 1) * BK;
    const int kB = (u + 2) * BK;
    const bool gA = (u + 1) < NT;
    const bool gB = (u + 2) < NT;
    const ushort* aR0 = sA + laneAOff + xo0;
    const ushort* aR1 = sA + laneAOff + xo1;
    bf16x8 bfr[4][2], af[2][2];

    // ---- q0: read bfr(8) + af rows 0-1; stage A(u+1)h0; MFMA acc[0-1] ----
    {
      const ushort* bR0 = sB + laneBOff + xo0;
      const ushort* bR1 = sB + laneBOff + xo1;
#pragma unroll
      for (int ni = 0; ni < 4; ++ni) {
        bfr[ni][0] = *(const bf16x8*)(bR0 + ni * 1024);
        bfr[ni][1] = *(const bf16x8*)(bR1 + ni * 1024);
      }
#pragma unroll
      for (int m2 = 0; m2 < 2; ++m2) {
        af[m2][0] = *(const bf16x8*)(aR0 + m2 * 1024);
        af[m2][1] = *(const bf16x8*)(aR1 + m2 * 1024);
      }
      if (gA) STAGE(dA, A, goffA, 0, kA);
      asm volatile("s_waitcnt lgkmcnt(8)" ::: "memory");   // partial pre-drain (12 reads)
      __builtin_amdgcn_sched_barrier(0);
      __builtin_amdgcn_s_barrier();
      asm volatile("s_waitcnt lgkmcnt(0)" ::: "memory");
      __builtin_amdgcn_sched_barrier(0);
      MFMA_CLUSTER(0);
      __builtin_amdgcn_s_barrier();
      __builtin_amdgcn_sched_barrier(0);
    }
    // ---- q1: af rows 2-3; stage A(u+1)h1; MFMA acc[2-3] ----
    {
#pragma unroll
      for (int m2 = 0; m2 < 2; ++m2) {
        af[m2][0] = *(const bf16x8*)(aR0 + (2 + m2) * 1024);
        af[m2][1] = *(const bf16x8*)(aR1 + (2 + m2) * 1024);
      }
      if (gA) STAGE(dA, A, goffA, 1, kA);
      __builtin_amdgcn_sched_barrier(0);
      __builtin_amdgcn_s_barrier();
      asm volatile("s_waitcnt lgkmcnt(0)" ::: "memory");
      __builtin_amdgcn_sched_barrier(0);
      MFMA_CLUSTER(2);
      __builtin_amdgcn_s_barrier();
      __builtin_amdgcn_sched_barrier(0);
    }
    // ---- q2: af rows 4-5; stage B(u+2)h0; MFMA acc[4-5] ----
    {
#pragma unroll
      for (int m2 = 0; m2 < 2; ++m2) {
        af[m2][0] = *(const bf16x8*)(aR0 + (4 + m2) * 1024);
        af[m2][1] = *(const bf16x8*)(aR1 + (4 + m2) * 1024);
      }
      if (gB) STAGE(dB, B, goffB, 0, kB);
      __builtin_amdgcn_sched_barrier(0);
      __builtin_amdgcn_s_barrier();
      asm volatile("s_waitcnt lgkmcnt(0)" ::: "memory");
      __builtin_amdgcn_sched_barrier(0);
      MFMA_CLUSTER(4);
      __builtin_amdgcn_s_barrier();
      __builtin_amdgcn_sched_barrier(0);
    }
    // ---- q3: af rows 6-7; stage B(u+2)h1; MFMA acc[6-7]; counted vmcnt ----
    {
#pragma unroll
      for (int m2 = 0; m2 < 2; ++m2) {
        af[m2][0] = *(const bf16x8*)(aR0 + (6 + m2) * 1024);
        af[m2][1] = *(const bf16x8*)(aR1 + (6 + m2) * 1024);
      }
      if (gB) STAGE(dB, B, goffB, 1, kB);
      __builtin_amdgcn_sched_barrier(0);
      __builtin_amdgcn_s_barrier();
      asm volatile("s_waitcnt lgkmcnt(0)" ::: "memory");
      __builtin_amdgcn_sched_barrier(0);
      MFMA_CLUSTER(6);
      if (gB) asm volatile("s_waitcnt vmcnt(4)" ::: "memory");  // A(u+1)+B(u+1) landed; B(u+2) flies
      else    asm volatile("s_waitcnt vmcnt(0)" ::: "memory");  // tail drain
      __builtin_amdgcn_s_barrier();
      __builtin_amdgcn_sched_barrier(0);
    }
  }

  const float alpha = scalep[0] * wscale2p[0];
#pragma unroll
  for (int mi = 0; mi < 8; ++mi)
#pragma unroll
    for (int ni = 0; ni < 4; ++ni) {
      const int col = n0 + wn * 64 + ni * 16 + fr;
      const int rbase = m0 + wm * 128 + mi * 16 + fq * 4;
#pragma unroll
      for (int r = 0; r < 4; ++r)
        C[(size_t)(rbase + r) * Ndim + col] = alpha * acc[mi][ni][r];
    }
}

// ---------------- launcher ----------------

extern "C" void kernel_launch(void* const* d_in, const int* in_sizes, int n_in,
                              void* d_out, int out_size, void* d_ws, size_t ws_size,
                              hipStream_t stream) {
  const float* x       = (const float*)d_in[0];
  const int*   w       = (const int*)d_in[1];
  const float* wscale  = (const float*)d_in[2];
  const float* wscale2 = (const float*)d_in[3];
  const float* scale   = (const float*)d_in[4];
  float* out = (float*)d_out;

  ushort* a_deq = (ushort*)d_ws;                       // 32 MB
  ushort* b_deq = a_deq + (size_t)Mdim * Kdim;         // 32 MB

  silu_quant_kernel<<<Mdim, 256, 0, stream>>>(x, a_deq, scale);
  wdeq_kernel<<<Ndim, 256, 0, stream>>>(w, wscale, b_deq);

  hipFuncSetAttribute((const void*)gemm256, hipFuncAttributeMaxDynamicSharedMemorySize, 131072);
  gemm256<<<(Mdim / BM) * (Ndim / BN), 512, 131072, stream>>>(a_deq, b_deq, out, scale, wscale2);
}

// Round 6
// 159.684 us; speedup vs baseline: 1.0519x; 1.0519x over previous
//
#include <hip/hip_runtime.h>
#include <math.h>

typedef unsigned int uint;
typedef unsigned short ushort;
typedef __attribute__((ext_vector_type(8))) short bf16x8;
typedef __attribute__((ext_vector_type(4))) float f32x4;

static constexpr int Mdim = 4096;
static constexpr int Ndim = 4096;
static constexpr int Kdim = 4096;
static constexpr int Hdim = 4096;

// ---------------- numerics helpers ----------------

__device__ __forceinline__ float fp8_round(float v) {
  float a = fabsf(v);
  float q;
  if (a >= 0x1p-6f) {
    uint u = __float_as_uint(a);
    int e = (int)(u >> 23) - 127;
    float quant = __uint_as_float((uint)(e - 3 + 127) << 23);
    q = rintf(a / quant) * quant;
    q = fminf(q, 448.f);
  } else {
    q = rintf(a * 512.f) * 0x1p-9f;
  }
  return copysignf(q, v);
}

__device__ __forceinline__ float e2m1_round(float t) {
  float a = fabsf(t);
  float q;
  if (a <= 0.25f) q = 0.f;
  else if (a <= 0.75f) q = 0.5f;
  else if (a <= 1.25f) q = 1.f;
  else if (a <= 1.75f) q = 1.5f;
  else if (a <= 2.5f)  q = 2.f;
  else if (a <= 3.5f)  q = 3.f;
  else if (a <= 5.f)   q = 4.f;
  else                 q = 6.f;
  return copysignf(q, t);
}

__device__ __forceinline__ float e2m1_decode(uint c) {
  uint m = c & 7u;
  float v;
  if (m == 0u) v = 0.f;
  else if (m == 1u) v = 0.5f;
  else v = __uint_as_float(((126u + (m >> 1)) << 23) | ((m & 1u) << 22));
  return (c & 8u) ? -v : v;
}

// ---------------- kernel 1: SiLU-mul + NVFP4 fake-quant -> bf16 a_deq ----------------

__global__ void silu_quant_kernel(const float* __restrict__ x, ushort* __restrict__ a_deq,
                                  const float* __restrict__ scalep) {
  const int g = blockIdx.x * 256 + threadIdx.x;
  const int row = g >> 8;
  const int blk = g & 255;
  const float gs = 1.0f / scalep[0];
  const float c6 = gs / 6.0f;
  const float* gp = x + (size_t)row * (2 * Hdim) + blk * 16;
  const float* up = gp + Hdim;
  float y[16];
  float amax = 0.f;
#pragma unroll
  for (int i = 0; i < 4; ++i) {
    float4 gv = ((const float4*)gp)[i];
    float4 uv = ((const float4*)up)[i];
    float ga[4] = {gv.x, gv.y, gv.z, gv.w};
    float ua[4] = {uv.x, uv.y, uv.z, uv.w};
#pragma unroll
    for (int j = 0; j < 4; ++j) {
      float xv = ga[j];
      float sig = 1.0f / (1.0f + expf(-xv));
      float yy = xv * sig * ua[j];
      y[i * 4 + j] = yy;
      amax = fmaxf(amax, fabsf(yy));
    }
  }
  const float sf = fp8_round(amax * c6);
  uint outp[8];
  if (sf > 0.f) {
    const float inv = gs / sf;
#pragma unroll
    for (int i = 0; i < 8; ++i) {
      float t0 = fminf(fmaxf(y[2 * i] * inv, -6.f), 6.f);
      float t1 = fminf(fmaxf(y[2 * i + 1] * inv, -6.f), 6.f);
      float d0 = e2m1_round(t0) * sf;
      float d1 = e2m1_round(t1) * sf;
      outp[i] = (__float_as_uint(d0) >> 16) | ((__float_as_uint(d1) >> 16) << 16);
    }
  } else {
#pragma unroll
    for (int i = 0; i < 8; ++i) outp[i] = 0u;
  }
  uint4* dst = (uint4*)(a_deq + (size_t)row * Hdim + blk * 16);
  dst[0] = (uint4){outp[0], outp[1], outp[2], outp[3]};
  dst[1] = (uint4){outp[4], outp[5], outp[6], outp[7]};
}

// ---------------- kernel 2: weight dequant -> bf16 b_deq ----------------

__global__ void wdeq_kernel(const int* __restrict__ w, const float* __restrict__ wscale,
                            ushort* __restrict__ b_deq) {
  const int g = blockIdx.x * 256 + threadIdx.x;
  const int n = g >> 8;
  const int blk = g & 255;
  const int4* wp = (const int4*)(w + (size_t)n * (Hdim / 2) + blk * 8);
  int4 w0 = wp[0], w1 = wp[1];
  int wb[8] = {w0.x, w0.y, w0.z, w0.w, w1.x, w1.y, w1.z, w1.w};
  const float ws = fp8_round(wscale[(size_t)n * (Hdim / 16) + blk]);
  uint outp[8];
#pragma unroll
  for (int i = 0; i < 8; ++i) {
    uint byte = (uint)wb[i] & 0xFFu;
    float vlo = e2m1_decode(byte & 15u) * ws;
    float vhi = e2m1_decode(byte >> 4) * ws;
    outp[i] = (__float_as_uint(vlo) >> 16) | ((__float_as_uint(vhi) >> 16) << 16);
  }
  uint4* dst = (uint4*)(b_deq + (size_t)n * Hdim + blk * 16);
  dst[0] = (uint4){outp[0], outp[1], outp[2], outp[3]};
  dst[1] = (uint4){outp[4], outp[5], outp[6], outp[7]};
}

// ---------------- kernel 3: 256x256 bf16 GEMM, balanced 8/4/4/8 reads + af ping-pong ----------------
// 8 waves (2M x 4N), BK=64, 2-slot LDS (128 KiB). Read distribution per K-tile:
// q0: bfr(8); q1: af1(4); q2: af2(4); q3: af3(4)+af0'(4, next A slot).
// af ping-pong: afA <- {af1, af3}, afB <- {af0', af2} (read one phase before use
// only for af0', which comes from the NEXT A slot after the vmcnt checkpoint).
// Stage ledger (tile u): q0 A(u+1)h0, q1 A(u+1)h1 (other A slot), q2 B(u+2)h0,
// q3 B(u+2)h1 (current B slot; B(u) reads ended at q0 close). vmcnt(2) at q2
// close forces A(u+1)+B(u+1) landed (needed: q3 reads af0' from A(u+1)),
// leaves B(u+2)h0 in flight. Pins: only sched_barrier(0) after each lgkmcnt(0).

#define BM 256
#define BN 256
#define BK 64
#define NT (Kdim / BK)
#define TILE_E (256 * 64)     // 16384 ushort = 32 KB

__device__ __forceinline__ void gload_lds16(const ushort* g, ushort* l) {
  __builtin_amdgcn_global_load_lds((const __attribute__((address_space(1))) void*)g,
                                   (__attribute__((address_space(3))) void*)l,
                                   16, 0, 0);
}

#define STAGE(dst, mat, goff, h, kcol)                                              \
  do {                                                                              \
    gload_lds16((mat) + (size_t)goff[(h)*2 + 0] + (kcol), (dst) + loff[(h)*2 + 0]); \
    gload_lds16((mat) + (size_t)goff[(h)*2 + 1] + (kcol), (dst) + loff[(h)*2 + 1]); \
  } while (0)

#define BAR()                                   \
  do {                                          \
    asm volatile("" ::: "memory");              \
    __builtin_amdgcn_s_barrier();               \
    asm volatile("" ::: "memory");              \
  } while (0)

__global__ __launch_bounds__(512, 2) void gemm256(const ushort* __restrict__ A,
                                                  const ushort* __restrict__ B,
                                                  float* __restrict__ C,
                                                  const float* __restrict__ scalep,
                                                  const float* __restrict__ wscale2p) {
  extern __shared__ __align__(16) ushort lds[];   // 131072 B
  const int tid = threadIdx.x;
  const int wave = tid >> 6;
  const int lane = tid & 63;
  const int wm = wave >> 2;
  const int wn = wave & 3;
  const int fr = lane & 15;
  const int fq = lane >> 4;

  const int wg = blockIdx.x;
  const int swz = (wg & 7) * 32 + (wg >> 3);      // 256 % 8 == 0 -> bijective
  const int m0 = (swz >> 4) * BM;
  const int n0 = (swz & 15) * BN;

  f32x4 acc[8][4];
#pragma unroll
  for (int i = 0; i < 8; ++i)
#pragma unroll
    for (int j = 0; j < 4; ++j) acc[i][j] = (f32x4){0.f, 0.f, 0.f, 0.f};

  ushort* A0s = lds;
  ushort* A1s = lds + TILE_E;
  ushort* B0s = lds + 2 * TILE_E;
  ushort* B1s = lds + 3 * TILE_E;

  int goffA[4], goffB[4], loff[4];
#pragma unroll
  for (int h = 0; h < 2; ++h)
#pragma unroll
    for (int rr = 0; rr < 2; ++rr) {
      const int idx = h * 2 + rr;
      const int rowb = h * 128 + rr * 64 + wave * 8;
      const int trow = rowb + (lane >> 3);
      const int sc = (lane & 7) ^ (trow & 7);
      goffA[idx] = (m0 + trow) * Kdim + sc * 8;
      goffB[idx] = (n0 + trow) * Kdim + sc * 8;
      loff[idx] = rowb * 64;
    }

  const int laneAOff = (wm * 128 + fr) * 64;
  const int laneBOff = (wn * 64 + fr) * 64;
  const int xo0 = (fq ^ (fr & 7)) * 8;
  const int xo1 = ((4 + fq) ^ (fr & 7)) * 8;

  // ---- prologue: A(0), B(0), B(1); vmcnt(4); pre-read af0 -> afB ----
  STAGE(A0s, A, goffA, 0, 0);  STAGE(A0s, A, goffA, 1, 0);
  STAGE(B0s, B, goffB, 0, 0);  STAGE(B0s, B, goffB, 1, 0);
  STAGE(B1s, B, goffB, 0, BK); STAGE(B1s, B, goffB, 1, BK);
  asm volatile("s_waitcnt vmcnt(4)" ::: "memory");
  BAR();

  bf16x8 afA[2][2], afB[2][2], bfr[4][2];
  {
    const ushort* a0 = A0s + laneAOff + xo0;
    const ushort* a1 = A0s + laneAOff + xo1;
#pragma unroll
    for (int m2 = 0; m2 < 2; ++m2) {
      afB[m2][0] = *(const bf16x8*)(a0 + m2 * 1024);
      afB[m2][1] = *(const bf16x8*)(a1 + m2 * 1024);
    }
  }

#define MFMA_Q(base, af)                                                         \
  do {                                                                           \
    __builtin_amdgcn_s_setprio(1);                                               \
    _Pragma("unroll")                                                            \
    for (int m2 = 0; m2 < 2; ++m2)                                               \
      _Pragma("unroll")                                                          \
      for (int ni = 0; ni < 4; ++ni)                                             \
        _Pragma("unroll")                                                        \
        for (int kk = 0; kk < 2; ++kk)                                           \
          acc[(base) + m2][ni] = __builtin_amdgcn_mfma_f32_16x16x32_bf16(        \
              af[m2][kk], bfr[ni][kk], acc[(base) + m2][ni], 0, 0, 0);           \
    __builtin_amdgcn_s_setprio(0);                                               \
  } while (0)

#define LGKM0()                                          \
  do {                                                   \
    asm volatile("s_waitcnt lgkmcnt(0)" ::: "memory");   \
    __builtin_amdgcn_sched_barrier(0);                   \
  } while (0)

  for (int u = 0; u < NT; ++u) {
    ushort* sA = (u & 1) ? A1s : A0s;
    ushort* sB = (u & 1) ? B1s : B0s;
    ushort* dA = (u & 1) ? A0s : A1s;
    const int kA = (u + 1) * BK;
    const int kB = (u + 2) * BK;
    const bool gA = (u + 1) < NT;
    const bool gB = (u + 2) < NT;
    const ushort* aR0 = sA + laneAOff + xo0;
    const ushort* aR1 = sA + laneAOff + xo1;

    // ---- q0: read bfr(8); stage A(u+1)h0; MFMA quad0 (afB) ----
    {
      const ushort* bR0 = sB + laneBOff + xo0;
      const ushort* bR1 = sB + laneBOff + xo1;
#pragma unroll
      for (int ni = 0; ni < 4; ++ni) {
        bfr[ni][0] = *(const bf16x8*)(bR0 + ni * 1024);
        bfr[ni][1] = *(const bf16x8*)(bR1 + ni * 1024);
      }
      if (gA) STAGE(dA, A, goffA, 0, kA);
      BAR();
      LGKM0();
      MFMA_Q(0, afB);
      BAR();
    }
    // ---- q1: read af1 -> afA; stage A(u+1)h1; MFMA quad1 ----
    {
#pragma unroll
      for (int m2 = 0; m2 < 2; ++m2) {
        afA[m2][0] = *(const bf16x8*)(aR0 + (2 + m2) * 1024);
        afA[m2][1] = *(const bf16x8*)(aR1 + (2 + m2) * 1024);
      }
      if (gA) STAGE(dA, A, goffA, 1, kA);
      BAR();
      LGKM0();
      MFMA_Q(2, afA);
      BAR();
    }
    // ---- q2: read af2 -> afB; stage B(u+2)h0; MFMA quad2; vmcnt checkpoint ----
    {
#pragma unroll
      for (int m2 = 0; m2 < 2; ++m2) {
        afB[m2][0] = *(const bf16x8*)(aR0 + (4 + m2) * 1024);
        afB[m2][1] = *(const bf16x8*)(aR1 + (4 + m2) * 1024);
      }
      if (gB) STAGE(sB, B, goffB, 0, kB);
      BAR();
      LGKM0();
      MFMA_Q(4, afB);
      if (gB) asm volatile("s_waitcnt vmcnt(2)" ::: "memory");  // A(u+1)+B(u+1) landed
      else    asm volatile("s_waitcnt vmcnt(0)" ::: "memory");
      BAR();
    }
    // ---- q3: read af3 -> afA, af0' -> afB (next A slot); stage B(u+2)h1; MFMA quad3 ----
    {
#pragma unroll
      for (int m2 = 0; m2 < 2; ++m2) {
        afA[m2][0] = *(const bf16x8*)(aR0 + (6 + m2) * 1024);
        afA[m2][1] = *(const bf16x8*)(aR1 + (6 + m2) * 1024);
      }
      if (gA) {
        const ushort* aN0 = dA + laneAOff + xo0;
        const ushort* aN1 = dA + laneAOff + xo1;
#pragma unroll
        for (int m2 = 0; m2 < 2; ++m2) {
          afB[m2][0] = *(const bf16x8*)(aN0 + m2 * 1024);
          afB[m2][1] = *(const bf16x8*)(aN1 + m2 * 1024);
        }
      }
      if (gB) STAGE(sB, B, goffB, 1, kB);
      BAR();
      LGKM0();
      MFMA_Q(6, afA);
      BAR();
    }
  }

  const float alpha = scalep[0] * wscale2p[0];
#pragma unroll
  for (int mi = 0; mi < 8; ++mi)
#pragma unroll
    for (int ni = 0; ni < 4; ++ni) {
      const int col = n0 + wn * 64 + ni * 16 + fr;
      const int rbase = m0 + wm * 128 + mi * 16 + fq * 4;
#pragma unroll
      for (int r = 0; r < 4; ++r)
        __builtin_nontemporal_store(alpha * acc[mi][ni][r],
                                    &C[(size_t)(rbase + r) * Ndim + col]);
    }
}

// ---------------- launcher ----------------

extern "C" void kernel_launch(void* const* d_in, const int* in_sizes, int n_in,
                              void* d_out, int out_size, void* d_ws, size_t ws_size,
                              hipStream_t stream) {
  const float* x       = (const float*)d_in[0];
  const int*   w       = (const int*)d_in[1];
  const float* wscale  = (const float*)d_in[2];
  const float* wscale2 = (const float*)d_in[3];
  const float* scale   = (const float*)d_in[4];
  float* out = (float*)d_out;

  ushort* a_deq = (ushort*)d_ws;                       // 32 MB
  ushort* b_deq = a_deq + (size_t)Mdim * Kdim;         // 32 MB

  silu_quant_kernel<<<Mdim, 256, 0, stream>>>(x, a_deq, scale);
  wdeq_kernel<<<Ndim, 256, 0, stream>>>(w, wscale, b_deq);

  (void)hipFuncSetAttribute((const void*)gemm256, hipFuncAttributeMaxDynamicSharedMemorySize, 131072);
  gemm256<<<(Mdim / BM) * (Ndim / BN), 512, 131072, stream>>>(a_deq, b_deq, out, scale, wscale2);
}